// Round 6
// baseline (805.731 us; speedup 1.0000x reference)
//
#include <hip/hip_runtime.h>

#define BLOCK 256
#define EPT 4   // edges per thread; 4*19 floats = 19 aligned float4 stores

typedef float vf4 __attribute__((ext_vector_type(4)));
typedef int   vi4 __attribute__((ext_vector_type(4)));

// Prepass: pack (pos.xyz, bitcast(batch)) into a 16B-aligned float4 table.
extern "C" __global__ void __launch_bounds__(BLOCK) pack_pos_batch(
    const float* __restrict__ pos,      // [N,3]
    const int*  __restrict__ batch,     // [N]
    vf4* __restrict__ pos4,             // [N] out
    int N)
{
    const int i = blockIdx.x * BLOCK + threadIdx.x;
    if (i < N) {
        vf4 v;
        v.x = pos[3 * i + 0];
        v.y = pos[3 * i + 1];
        v.z = pos[3 * i + 2];
        v.w = __int_as_float(batch[i]);
        pos4[i] = v;
    }
}

template <bool PACKED>
__global__ void __launch_bounds__(BLOCK) edge_encoding_kernel(
    const float* __restrict__ pos,      // [N,3] (fallback)
    const vf4*   __restrict__ pos4,     // [N] packed
    const float* __restrict__ cells,    // [G,3,3] = 144 f32 (G=16)
    const int*   __restrict__ eidx,     // [2,E]
    const int*   __restrict__ pidx,     // [E]
    const int*   __restrict__ batch,    // [N] (fallback)
    float* __restrict__ out,            // [E,19]
    int E)
{
    // (g,p) -> shift vector table: 16 graphs x 27 shifts, one ds_read_b128/edge.
    // Replaces per-edge div/mod decode + 9 LDS reads + 9 FMAs.
    __shared__ vf4 s_t[16 * 27];        // 6912 B

    const int tid = threadIdx.x;
    for (int c = tid; c < 16 * 27; c += BLOCK) {
        const int g = c / 27, p = c % 27;
        const float f0 = (float)(p / 9 - 1);
        const float f1 = (float)((p / 3) % 3 - 1);
        const float f2 = (float)(p % 3 - 1);
        const float* C = cells + g * 9;
        vf4 t;
        t.x = C[0]*f0 + C[3]*f1 + C[6]*f2;
        t.y = C[1]*f0 + C[4]*f1 + C[7]*f2;
        t.z = C[2]*f0 + C[5]*f1 + C[8]*f2;
        t.w = 0.0f;
        s_t[c] = t;
    }
    __syncthreads();   // only barrier in the kernel; nothing in flight yet

    const long long gtid = (long long)blockIdx.x * BLOCK + tid;
    const long long e0   = gtid * EPT;
    if (e0 >= E) return;

    const bool full = (e0 + EPT <= (long long)E);
    const bool evec = ((E & 3) == 0);   // vector idx loads need eidx+E 16B-aligned

    // ---- index loads: 3 x dwordx4 per 4 edges (nt: streamed once) ----
    int src[EPT], dst[EPT], pp[EPT];
    if (full && evec) {
        const vi4 s = __builtin_nontemporal_load((const vi4*)(eidx + e0));
        const vi4 d = __builtin_nontemporal_load((const vi4*)(eidx + E + e0));
        const vi4 q = __builtin_nontemporal_load((const vi4*)(pidx + e0));
        src[0]=s.x; src[1]=s.y; src[2]=s.z; src[3]=s.w;
        dst[0]=d.x; dst[1]=d.y; dst[2]=d.z; dst[3]=d.w;
        pp[0]=q.x;  pp[1]=q.y;  pp[2]=q.z;  pp[3]=q.w;
    } else {
        #pragma unroll
        for (int k = 0; k < EPT; ++k) {
            long long e = e0 + k; if (e >= E) e = E - 1;   // clamp; rows not stored
            src[k] = eidx[e];
            dst[k] = eidx[E + e];
            pp[k]  = pidx[e];
        }
    }

    // ---- 8 independent gathers, all in flight together ----
    vf4 ps[EPT], pd[EPT];
    #pragma unroll
    for (int k = 0; k < EPT; ++k) {
        if (PACKED) {
            ps[k] = pos4[src[k]];
            pd[k] = pos4[dst[k]];
        } else {
            const int s = src[k], d = dst[k];
            ps[k].x = pos[3*s+0]; ps[k].y = pos[3*s+1]; ps[k].z = pos[3*s+2];
            ps[k].w = __int_as_float(batch[s]);
            pd[k].x = pos[3*d+0]; pd[k].y = pos[3*d+1]; pd[k].z = pos[3*d+2];
            pd[k].w = 0.0f;
        }
    }

    const float s3  = 1.7320508075688772f;
    const float s5  = 2.2360679774997896f;
    const float s15 = 3.872983346207417f;

    float buf[EPT * 19];                 // all indices static after unroll -> registers
    #pragma unroll
    for (int k = 0; k < EPT; ++k) {
        const int g = __float_as_int(ps[k].w);
        const vf4 t = s_t[g * 27 + pp[k]];

        const float vx = ps[k].x - pd[k].x + t.x;
        const float vy = ps[k].y - pd[k].y + t.y;
        const float vz = ps[k].z - pd[k].z + t.z;

        const float len  = sqrtf(vx*vx + vy*vy + vz*vz);
        const float invl = __builtin_amdgcn_rcpf(fmaxf(len, 1e-6f));
        const float x = vx * invl, y = vy * invl, z = vz * invl;

        float* row = buf + k * 19;
        row[0] = len;
        row[1] = 1.0f;
        row[2] = s3 * x;
        row[3] = s3 * y;
        row[4] = s3 * z;
        row[5] = s15 * x * z;
        row[6] = s15 * x * y;
        row[7] = s5  * (y*y - 0.5f*(x*x + z*z));
        row[8] = s15 * y * z;
        row[9] = 0.5f * s15 * (z*z - x*x);

        // polynomial cutoff (P=6): 1 - 28 x^6 + 48 x^7 - 21 x^8
        const float xc = fminf(len * (1.0f/6.0f), 1.0f);
        const float x3 = xc * xc * xc;
        const float x6 = x3 * x3;
        const float cut = fmaf(x6, fmaf(xc, fmaf(-21.0f, xc, 48.0f), -28.0f), 1.0f);
        row[10] = cut;

        // bessel via Chebyshev recurrence; native sin/cos (~1e-5 err, tol 0.125)
        const float safe = fminf(fmaxf(len, 1e-6f), 6.0f);
        const float a = safe * 0.5235987755982988f;   // pi/6
        const float sa = __sinf(a);
        const float ca = __cosf(a);
        const float w = cut * 0.5f * __builtin_amdgcn_rcpf(safe);
        const float two_ca = 2.0f * ca;
        float s_prev = 0.0f, s_cur = sa;
        row[11] = s_cur * w;
        #pragma unroll
        for (int n = 2; n <= 8; ++n) {
            const float s_next = two_ca * s_cur - s_prev;
            s_prev = s_cur;
            s_cur  = s_next;
            row[10 + n] = s_cur * w;
        }
    }

    // ---- stores: 4*19 floats = 19 aligned float4s (base = 304B * gtid) ----
    float* gout = out + e0 * 19;
    if (full) {
        #pragma unroll
        for (int i = 0; i < 19; ++i) {
            vf4 v;
            v.x = buf[4*i+0]; v.y = buf[4*i+1]; v.z = buf[4*i+2]; v.w = buf[4*i+3];
            __builtin_nontemporal_store(v, (vf4*)gout + i);
        }
    } else {
        const int nvalid = (int)(E - e0);
        for (int k = 0; k < nvalid; ++k)
            for (int j = 0; j < 19; ++j)
                gout[k*19 + j] = buf[k*19 + j];
    }
}

extern "C" void kernel_launch(void* const* d_in, const int* in_sizes, int n_in,
                              void* d_out, int out_size, void* d_ws, size_t ws_size,
                              hipStream_t stream) {
    const float* pos   = (const float*)d_in[0];
    const float* cells = (const float*)d_in[1];
    const int*   eidx  = (const int*)d_in[2];
    const int*   pidx  = (const int*)d_in[3];
    const int*   batch = (const int*)d_in[4];
    float* out = (float*)d_out;

    const int E = in_sizes[3];   // periodic_index count = num edges
    const int N = in_sizes[4];   // batch count = num nodes
    const int grid = (int)(((long long)E + BLOCK * EPT - 1) / (BLOCK * EPT));

    if (d_ws != nullptr && ws_size >= (size_t)N * sizeof(vf4)) {
        vf4* pos4 = (vf4*)d_ws;
        const int pgrid = (N + BLOCK - 1) / BLOCK;
        pack_pos_batch<<<pgrid, BLOCK, 0, stream>>>(pos, batch, pos4, N);
        edge_encoding_kernel<true><<<grid, BLOCK, 0, stream>>>(
            pos, pos4, cells, eidx, pidx, batch, out, E);
    } else {
        edge_encoding_kernel<false><<<grid, BLOCK, 0, stream>>>(
            pos, nullptr, cells, eidx, pidx, batch, out, E);
    }
}

// Round 8
// 316.534 us; speedup vs baseline: 2.5455x; 2.5455x over previous
//
#include <hip/hip_runtime.h>

#define BLOCK 256
#define EPT 4            // edges per thread, strided by 256 within the block tile
#define TILE (BLOCK * EPT)   // 1024 edges per block

typedef float vf4 __attribute__((ext_vector_type(4)));

// Prepass: pack (pos.xyz, bitcast(batch)) into a 16B-aligned float4 table.
extern "C" __global__ void __launch_bounds__(BLOCK) pack_pos_batch(
    const float* __restrict__ pos,      // [N,3]
    const int*  __restrict__ batch,     // [N]
    vf4* __restrict__ pos4,             // [N] out
    int N)
{
    const int i = blockIdx.x * BLOCK + threadIdx.x;
    if (i < N) {
        vf4 v;
        v.x = pos[3 * i + 0];
        v.y = pos[3 * i + 1];
        v.z = pos[3 * i + 2];
        v.w = __int_as_float(batch[i]);
        pos4[i] = v;
    }
}

template <bool PACKED>
__global__ void __launch_bounds__(BLOCK) edge_encoding_kernel(
    const float* __restrict__ pos,      // [N,3] (fallback)
    const vf4*   __restrict__ pos4,     // [N] packed
    const float* __restrict__ cells,    // [G,3,3] = 144 f32 (G=16)
    const int*   __restrict__ eidx,     // [2,E]
    const int*   __restrict__ pidx,     // [E]
    const int*   __restrict__ batch,    // [N] (fallback)
    float* __restrict__ out,            // [E,19]
    int E)
{
    // (g,p) -> shift vector table (R6: removes per-edge div/mod + einsum)
    __shared__ vf4 s_t[16 * 27];                      // 6912 B
    __shared__ __align__(16) float s_out[BLOCK * 19]; // 19456 B

    const int tid = threadIdx.x;
    for (int c = tid; c < 16 * 27; c += BLOCK) {
        const int g = c / 27, p = c % 27;
        const float f0 = (float)(p / 9 - 1);
        const float f1 = (float)((p / 3) % 3 - 1);
        const float f2 = (float)(p % 3 - 1);
        const float* C = cells + g * 9;
        vf4 t;
        t.x = C[0]*f0 + C[3]*f1 + C[6]*f2;
        t.y = C[1]*f0 + C[4]*f1 + C[7]*f2;
        t.z = C[2]*f0 + C[5]*f1 + C[8]*f2;
        t.w = 0.0f;
        s_t[c] = t;
    }
    __syncthreads();   // nothing in VMEM flight yet -> cheap drain

    const long long b0 = (long long)blockIdx.x * TILE;

    // ---- all index loads + gathers issued up front (max MLP, no barrier after) ----
    int src[EPT], dst[EPT], pp[EPT];
    #pragma unroll
    for (int r = 0; r < EPT; ++r) {
        long long e = b0 + (long long)r * BLOCK + tid;
        if (e >= E) e = E - 1;                 // clamped rows are never copied out
        src[r] = __builtin_nontemporal_load(eidx + e);
        dst[r] = __builtin_nontemporal_load(eidx + E + e);
        pp[r]  = __builtin_nontemporal_load(pidx + e);
    }
    vf4 ps[EPT], pd[EPT];
    #pragma unroll
    for (int r = 0; r < EPT; ++r) {
        if (PACKED) {
            ps[r] = pos4[src[r]];
            pd[r] = pos4[dst[r]];
        } else {
            const int s = src[r], d = dst[r];
            ps[r].x = pos[3*s+0]; ps[r].y = pos[3*s+1]; ps[r].z = pos[3*s+2];
            ps[r].w = __int_as_float(batch[s]);
            pd[r].x = pos[3*d+0]; pd[r].y = pos[3*d+1]; pd[r].z = pos[3*d+2];
            pd[r].w = 0.0f;
        }
    }

    const float s3  = 1.7320508075688772f;
    const float s5  = 2.2360679774997896f;
    const float s15 = 3.872983346207417f;

    // ---- 4 chunks: compute -> LDS stage -> full-line coalesced copyout ----
    #pragma unroll
    for (int c = 0; c < EPT; ++c) {
        float row[19];
        {
            const int g = __float_as_int(ps[c].w);
            const vf4 t = s_t[g * 27 + pp[c]];

            const float vx = ps[c].x - pd[c].x + t.x;
            const float vy = ps[c].y - pd[c].y + t.y;
            const float vz = ps[c].z - pd[c].z + t.z;

            const float len  = sqrtf(vx*vx + vy*vy + vz*vz);
            const float invl = __builtin_amdgcn_rcpf(fmaxf(len, 1e-6f));
            const float x = vx * invl, y = vy * invl, z = vz * invl;

            row[0] = len;
            row[1] = 1.0f;
            row[2] = s3 * x;
            row[3] = s3 * y;
            row[4] = s3 * z;
            row[5] = s15 * x * z;
            row[6] = s15 * x * y;
            row[7] = s5  * (y*y - 0.5f*(x*x + z*z));
            row[8] = s15 * y * z;
            row[9] = 0.5f * s15 * (z*z - x*x);

            // polynomial cutoff (P=6): 1 - 28 x^6 + 48 x^7 - 21 x^8
            const float xc = fminf(len * (1.0f/6.0f), 1.0f);
            const float x3 = xc * xc * xc;
            const float x6 = x3 * x3;
            const float cut = fmaf(x6, fmaf(xc, fmaf(-21.0f, xc, 48.0f), -28.0f), 1.0f);
            row[10] = cut;

            // bessel via Chebyshev recurrence; native sin/cos (~1e-5 err, tol 0.125)
            const float safe = fminf(fmaxf(len, 1e-6f), 6.0f);
            const float a = safe * 0.5235987755982988f;   // pi/6
            const float sa = __sinf(a);
            const float ca = __cosf(a);
            const float w = cut * 0.5f * __builtin_amdgcn_rcpf(safe);
            const float two_ca = 2.0f * ca;
            float s_prev = 0.0f, s_cur = sa;
            row[11] = s_cur * w;
            #pragma unroll
            for (int n = 2; n <= 8; ++n) {
                const float s_next = two_ca * s_cur - s_prev;
                s_prev = s_cur;
                s_cur  = s_next;
                row[10 + n] = s_cur * w;
            }
        }

        if (c > 0) __syncthreads();   // prev chunk's copyout reads done before overwrite

        // stride-19 LDS stage: gcd(19,32)=1 -> 2-way max (free)
        #pragma unroll
        for (int j = 0; j < 19; ++j) s_out[tid * 19 + j] = row[j];
        __syncthreads();

        // copyout chunk c: 256 rows, wave-consecutive float4s = 1 KB/instr full lines
        const long long base_e = b0 + (long long)c * BLOCK;
        if (base_e < E) {
            const int nvalid  = (int)min((long long)BLOCK, (long long)E - base_e);
            const int nfloats = nvalid * 19;
            float* gout = out + base_e * 19;          // 19456B-multiple: 16B aligned
            const int n4 = nfloats >> 2;
            const vf4* s4 = reinterpret_cast<const vf4*>(s_out);
            vf4* g4 = reinterpret_cast<vf4*>(gout);
            for (int i = tid; i < n4; i += BLOCK)
                __builtin_nontemporal_store(s4[i], g4 + i);
            for (int i = (n4 << 2) + tid; i < nfloats; i += BLOCK)
                __builtin_nontemporal_store(s_out[i], gout + i);
        }
    }
}

extern "C" void kernel_launch(void* const* d_in, const int* in_sizes, int n_in,
                              void* d_out, int out_size, void* d_ws, size_t ws_size,
                              hipStream_t stream) {
    const float* pos   = (const float*)d_in[0];
    const float* cells = (const float*)d_in[1];
    const int*   eidx  = (const int*)d_in[2];
    const int*   pidx  = (const int*)d_in[3];
    const int*   batch = (const int*)d_in[4];
    float* out = (float*)d_out;

    const int E = in_sizes[3];   // periodic_index count = num edges
    const int N = in_sizes[4];   // batch count = num nodes
    const int grid = (int)(((long long)E + TILE - 1) / TILE);

    if (d_ws != nullptr && ws_size >= (size_t)N * sizeof(vf4)) {
        vf4* pos4 = (vf4*)d_ws;
        const int pgrid = (N + BLOCK - 1) / BLOCK;
        pack_pos_batch<<<pgrid, BLOCK, 0, stream>>>(pos, batch, pos4, N);
        edge_encoding_kernel<true><<<grid, BLOCK, 0, stream>>>(
            pos, pos4, cells, eidx, pidx, batch, out, E);
    } else {
        edge_encoding_kernel<false><<<grid, BLOCK, 0, stream>>>(
            pos, nullptr, cells, eidx, pidx, batch, out, E);
    }
}